// Round 6
// baseline (400.864 us; speedup 1.0000x reference)
//
#include <hip/hip_runtime.h>
#include <stdint.h>

#define DEV __device__ __forceinline__

typedef __attribute__((ext_vector_type(8))) short bf16x8;
typedef __attribute__((ext_vector_type(4))) float f32x4;
typedef __attribute__((ext_vector_type(4))) short s16x4;

DEV short f2bf(float f) {
    union { float f; unsigned u; } v; v.f = f;
    unsigned r = v.u + 0x7fffu + ((v.u >> 16) & 1u);
    return (short)(r >> 16);
}

// packed f32x2 -> bf16x2 (RNE), single VALU op
DEV uint32_t cvtpk(float lo, float hi) {
    uint32_t r;
    asm("v_cvt_pk_bf16_f32 %0, %1, %2" : "=v"(r) : "v"(lo), "v"(hi));
    return r;
}

typedef const unsigned int __attribute__((address_space(1)))* gp1;
typedef unsigned int __attribute__((address_space(3)))* lp3;

DEV void gload16(const void* g, void* l) {
    __builtin_amdgcn_global_load_lds((gp1)g, (lp3)l, 16, 0, 0);
}

DEV void bar()           { asm volatile("s_barrier" ::: "memory"); }
DEV void wait4_barrier() { asm volatile("s_waitcnt vmcnt(4)\ns_barrier" ::: "memory"); }
DEV void wait2_barrier() { asm volatile("s_waitcnt vmcnt(2)\ns_barrier" ::: "memory"); }
DEV void wait0_barrier() { asm volatile("s_waitcnt vmcnt(0)\ns_barrier" ::: "memory"); }

// ---------------- weight transpose + fp32->bf16 convert ----------------
__global__ __launch_bounds__(256) void tcvt(
    const float* __restrict__ W, short* __restrict__ WT, int K, int N)
{
    __shared__ float t[32][33];
    int n0 = blockIdx.x * 32, k0 = blockIdx.y * 32;
    int tx = threadIdx.x & 31, ty = threadIdx.x >> 5;
#pragma unroll
    for (int i = 0; i < 32; i += 8)
        t[ty + i][tx] = W[(size_t)(k0 + ty + i) * N + n0 + tx];
    __syncthreads();
#pragma unroll
    for (int i = 0; i < 32; i += 8)
        WT[(size_t)(n0 + ty + i) * K + k0 + tx] = f2bf(t[tx][ty + i]);
}

// ---------------- LayerNorm fp32 -> bf16, one wave per row (C=768) -----
__global__ __launch_bounds__(256) void ln_bf16(
    const float* __restrict__ x, const float* __restrict__ gam,
    const float* __restrict__ bet, short* __restrict__ out)
{
    const int w = threadIdx.x >> 6, lane = threadIdx.x & 63;
    const size_t row = (size_t)blockIdx.x * 4 + w;
    const float* xr = x + row * 768;
    float4 v[3];
    float s = 0.f, ss = 0.f;
#pragma unroll
    for (int k = 0; k < 3; ++k) {
        v[k] = *(const float4*)(xr + k * 256 + lane * 4);
        s  += v[k].x + v[k].y + v[k].z + v[k].w;
        ss += v[k].x * v[k].x + v[k].y * v[k].y + v[k].z * v[k].z + v[k].w * v[k].w;
    }
#pragma unroll
    for (int i = 1; i < 64; i <<= 1) { s += __shfl_xor(s, i, 64); ss += __shfl_xor(ss, i, 64); }
    const float inv = 1.f / 768.f;
    float mu = s * inv;
    float var = ss * inv - mu * mu;
    float rstd = rsqrtf(var + 1e-5f);
#pragma unroll
    for (int k = 0; k < 3; ++k) {
        int c = k * 256 + lane * 4;
        float vv[4] = { v[k].x, v[k].y, v[k].z, v[k].w };
        s16x4 o;
#pragma unroll
        for (int j = 0; j < 4; ++j)
            o[j] = f2bf((vv[j] - mu) * rstd * gam[c + j] + bet[c + j]);
        *(s16x4*)(out + row * 768 + c) = o;
    }
}

// ================= 256x256 / BK=64 8-phase GEMM (8 waves) ==============
// A[M,K] * Bt[N,K]^T, double-buffered 128KiB dynamic LDS.
// Per K-tile: 4 phases; phase q = {ds_read af[2q..2q+1][kk0,kk1] (+all bf
// at q0, register-cached) | stage 2 chunks | s_barrier | 16 MFMA | s_barrier}.
// Chunk = 8KB = 64 rows x 128B (1 gload16/thread). Region windows (derived):
//   A-chunk rows[64c..64c+64) of tile u read at phases {2c,2c+1}; B read q0.
// Stage plan during tile u (buf p=u&1): q0: A1,A3(u+1)->p^1 (p^1's reads
// ended at u-1.q3); q1: B0,B1(u+1); q2: B2,B3(u+1); q3: A0,A2(u+2)->p
// (p's A0/A2 reads ended q1). One vmcnt(2) per tile at q3's barrier leaves
// only q3's 2 loads in flight -> all of tile u+1 landed before its q0.
// MODE 0: QKV scatter (q scaled 0.125*log2e, v transposed [B,H,D,N])
// MODE 2: out_bf16 = gelu(acc + bias)
template<int MODE>
__global__ __launch_bounds__(512, 2) void gemm256(
    const short* __restrict__ A, const short* __restrict__ Bt,
    int M, int N, int K,
    const float* __restrict__ bias,
    short* __restrict__ outb,
    short* __restrict__ qo, short* __restrict__ ko, short* __restrict__ vo)
{
    extern __shared__ __align__(16) char smem[];
    char* const AsB[2] = { smem,         smem + 32768 };
    char* const BsB[2] = { smem + 65536, smem + 98304 };
    const int tid = threadIdx.x;
    const int w = tid >> 6, lane = tid & 63;
    const int g = lane >> 4, l15 = lane & 15;
    const int wr = w >> 2, wc = w & 3;            // 2M x 4N waves
    const int brow = blockIdx.x * 256, bcol = blockIdx.y * 256;
    const int wbase = w * 1024;

    f32x4 acc[8][4] = {};

    auto stageA = [&](int buf, int kt, int c) {
        int base = c * 8192 + wbase;              // wave-uniform LDS dest
        int L = base + lane * 16;
        int r = L >> 7, b = L & 127;              // 128B rows
        int bs = b ^ ((r & 7) << 4);              // inverse-swizzled source
        gload16((const char*)(A + (size_t)(brow + r) * K + kt * 64) + bs, AsB[buf] + base);
    };
    auto stageB = [&](int buf, int kt, int c) {
        int base = c * 8192 + wbase;
        int L = base + lane * 16;
        int r = L >> 7, b = L & 127;
        int bs = b ^ ((r & 7) << 4);
        gload16((const char*)(Bt + (size_t)(bcol + r) * K + kt * 64) + bs, BsB[buf] + base);
    };
    auto ldA = [&](int buf, int m, int kk) -> bf16x8 {
        int r = wr * 128 + m * 16 + l15;
        int off = (kk * 64 + g * 16) ^ ((r & 7) << 4);
        return *(const bf16x8*)(AsB[buf] + r * 128 + off);
    };
    auto ldB = [&](int buf, int n, int kk) -> bf16x8 {
        int r = wc * 64 + n * 16 + l15;
        int off = (kk * 64 + g * 16) ^ ((r & 7) << 4);
        return *(const bf16x8*)(BsB[buf] + r * 128 + off);
    };

    const int NT = K >> 6;                        // even (12 or 48)

    // prologue: all of tile 0, then A0,A2 of tile 1 (the 2 newest)
    stageA(0, 0, 0); stageA(0, 0, 1); stageA(0, 0, 2); stageA(0, 0, 3);
    stageB(0, 0, 0); stageB(0, 0, 1); stageB(0, 0, 2); stageB(0, 0, 3);
    stageA(1, 1, 0); stageA(1, 1, 2);
    wait2_barrier();                              // tile0 landed; 2 in flight

    bf16x8 bfr[4][2];

#define PHASE(BUF, Q, STAGES) do {                                             \
    bf16x8 a0 = ldA(BUF, 2*(Q),   0);                                          \
    bf16x8 a1 = ldA(BUF, 2*(Q),   1);                                          \
    bf16x8 a2 = ldA(BUF, 2*(Q)+1, 0);                                          \
    bf16x8 a3 = ldA(BUF, 2*(Q)+1, 1);                                          \
    if ((Q) == 0) {                                                            \
        _Pragma("unroll")                                                      \
        for (int n = 0; n < 4; ++n) {                                          \
            bfr[n][0] = ldB(BUF, n, 0);                                        \
            bfr[n][1] = ldB(BUF, n, 1);                                        \
        }                                                                      \
    }                                                                          \
    STAGES;                                                                    \
    bar();                                                                     \
    __builtin_amdgcn_s_setprio(1);                                             \
    _Pragma("unroll")                                                          \
    for (int n = 0; n < 4; ++n) {                                              \
        acc[2*(Q)][n]   = __builtin_amdgcn_mfma_f32_16x16x32_bf16(a0, bfr[n][0], acc[2*(Q)][n],   0, 0, 0); \
        acc[2*(Q)][n]   = __builtin_amdgcn_mfma_f32_16x16x32_bf16(a1, bfr[n][1], acc[2*(Q)][n],   0, 0, 0); \
        acc[2*(Q)+1][n] = __builtin_amdgcn_mfma_f32_16x16x32_bf16(a2, bfr[n][0], acc[2*(Q)+1][n], 0, 0, 0); \
        acc[2*(Q)+1][n] = __builtin_amdgcn_mfma_f32_16x16x32_bf16(a3, bfr[n][1], acc[2*(Q)+1][n], 0, 0, 0); \
    }                                                                          \
    __builtin_amdgcn_s_setprio(0);                                             \
} while (0)

#define TILE(BUF, U) do {                                                      \
    PHASE(BUF, 0, if ((U)+1 < NT) { stageA((BUF)^1, (U)+1, 1); stageA((BUF)^1, (U)+1, 3); }); \
    bar();                                                                     \
    PHASE(BUF, 1, if ((U)+1 < NT) { stageB((BUF)^1, (U)+1, 0); stageB((BUF)^1, (U)+1, 1); }); \
    bar();                                                                     \
    PHASE(BUF, 2, if ((U)+1 < NT) { stageB((BUF)^1, (U)+1, 2); stageB((BUF)^1, (U)+1, 3); }); \
    bar();                                                                     \
    PHASE(BUF, 3, if ((U)+2 < NT) { stageA((BUF),   (U)+2, 0); stageA((BUF),   (U)+2, 2); }); \
    if ((U)+2 < NT)      wait2_barrier();                                      \
    else if ((U)+1 < NT) wait0_barrier();                                      \
    else                 bar();                                                \
} while (0)

    for (int tt = 0; tt < NT; tt += 2) { TILE(0, tt); TILE(1, tt + 1); }
#undef PHASE
#undef TILE

#pragma unroll
    for (int m = 0; m < 8; ++m) {
#pragma unroll
        for (int n = 0; n < 4; ++n) {
#pragma unroll
            for (int j = 0; j < 4; ++j) {
                int r = brow + wr * 128 + m * 16 + g * 4 + j;
                int c = bcol + wc * 64 + n * 16 + l15;
                float v = acc[m][n][j];
                if (MODE == 0) {
                    int which = c / 768, cc = c % 768;
                    int h = cc >> 6, d = cc & 63;
                    int b_ = r >> 11, nn = r & 2047;
                    size_t bh = (size_t)b_ * 12 + h;
                    // Q pre-scaled by 0.125*log2(e) so attention uses exp2
                    if (which == 0)      qo[(bh * 2048 + nn) * 64 + d] = f2bf(v * 0.18033688011112042f);
                    else if (which == 1) ko[(bh * 2048 + nn) * 64 + d] = f2bf(v);
                    else                 vo[(bh * 64 + d) * 2048 + nn] = f2bf(v);
                } else {
                    float t = v + bias[c];
                    float ge = 0.5f * t * (1.0f + erff(t * 0.70710678118654752f));
                    outb[(size_t)r * N + c] = f2bf(ge);
                }
            }
        }
    }
}

// ---------------- 128x128x32 bf16 GEMM (kept for N=768 shapes) ----------
// Triple-buffered LDS, distance-2 prefetch, counted vmcnt(4) barriers.
// MODE 1: out_f32 = acc + bias + resid
template<int MODE>
__global__ __launch_bounds__(256, 3) void gemm_bf16(
    const short* __restrict__ A, const short* __restrict__ Bt,
    int M, int N, int K,
    const float* __restrict__ bias, const float* __restrict__ resid,
    float* __restrict__ outf)
{
    __shared__ __align__(16) short As[3][128 * 32];
    __shared__ __align__(16) short Bs[3][128 * 32];
    const int tid = threadIdx.x;
    const int w = tid >> 6, lane = tid & 63;
    const int g = lane >> 4, l15 = lane & 15;
    const int brow = blockIdx.x * 128, bcol = blockIdx.y * 128;
    const int wr = w >> 1, wc = w & 1;
    f32x4 acc[4][4] = {};

    auto stage = [&](int buf, int kt) {
#pragma unroll
        for (int c = 0; c < 2; ++c) {
            int base = w * 2048 + c * 1024;
            int L = base + lane * 16;
            int r = L >> 6;
            int b = L & 63;
            int bs = b ^ (((r >> 1) & 3) << 4);
            gload16((const char*)(A  + (size_t)(brow + r) * K + kt) + bs, (char*)&As[buf][0] + base);
            gload16((const char*)(Bt + (size_t)(bcol + r) * K + kt) + bs, (char*)&Bs[buf][0] + base);
        }
    };

    const int KT = K >> 5;
    stage(0, 0);
    stage(1, 32);
    wait4_barrier();

    int cur = 0;
    for (int ki = 0; ki < KT; ++ki) {
        if (ki + 2 < KT) {
            int nxt2 = cur + 2; if (nxt2 >= 3) nxt2 -= 3;
            stage(nxt2, (ki + 2) << 5);
        }
        bf16x8 af[4], bfg[4];
#pragma unroll
        for (int m = 0; m < 4; ++m) {
            int r = wr * 64 + m * 16 + l15;
            af[m] = *(const bf16x8*)((const char*)&As[cur][0] + r * 64 + ((g * 16) ^ (((r >> 1) & 3) << 4)));
        }
#pragma unroll
        for (int n = 0; n < 4; ++n) {
            int r = wc * 64 + n * 16 + l15;
            bfg[n] = *(const bf16x8*)((const char*)&Bs[cur][0] + r * 64 + ((g * 16) ^ (((r >> 1) & 3) << 4)));
        }
#pragma unroll
        for (int m = 0; m < 4; ++m)
#pragma unroll
            for (int n = 0; n < 4; ++n)
                acc[m][n] = __builtin_amdgcn_mfma_f32_16x16x32_bf16(af[m], bfg[n], acc[m][n], 0, 0, 0);
        if (ki + 1 < KT) {
            if (ki + 2 < KT) wait4_barrier();
            else             wait0_barrier();
        }
        ++cur; if (cur >= 3) cur -= 3;
    }

#pragma unroll
    for (int m = 0; m < 4; ++m)
#pragma unroll
        for (int n = 0; n < 4; ++n)
#pragma unroll
            for (int j = 0; j < 4; ++j) {
                int r = brow + wr * 64 + m * 16 + g * 4 + j;
                int c = bcol + wc * 64 + n * 16 + l15;
                outf[(size_t)r * N + c] = acc[m][n][j] + bias[c] + resid[(size_t)r * N + c];
            }
}

// ---------------- flash attention (streaming, swapped-QK softmax) ------
__global__ __launch_bounds__(256, 4) void attn_fwd(
    const short* __restrict__ Q, const short* __restrict__ Kg,
    const short* __restrict__ Vt, short* __restrict__ Y)
{
    __shared__ __align__(16) short Kl[4][32 * 64];   // 32 keys x 128B
    __shared__ __align__(16) short Vl[4][64 * 32];   // 64 d    x  64B
    __shared__ __align__(16) short Pl[4][32 * 32];   // 32 q    x  64B (per wave)
    const int tid = threadIdx.x, w = tid >> 6, lane = tid & 63;
    const int g = lane >> 4, l15 = lane & 15;
    const int bh = blockIdx.y;
    const int q0 = blockIdx.x * 128 + w * 32;
    const short* Qb = Q  + (size_t)bh * 2048 * 64;
    const short* Kb = Kg + (size_t)bh * 2048 * 64;
    const short* Vb = Vt + (size_t)bh * 64 * 2048;

    bf16x8 qf[2][2];
#pragma unroll
    for (int m = 0; m < 2; ++m)
#pragma unroll
        for (int kk = 0; kk < 2; ++kk)
            qf[m][kk] = *(const bf16x8*)(Qb + (size_t)(q0 + m * 16 + l15) * 64 + kk * 32 + g * 8);

    f32x4 accO[2][4] = {};
    float lpart[2] = { 0.f, 0.f };

    auto stage = [&](int buf, int k0) {
        int bb = w * 1024;
        int L = bb + lane * 16;
        int rk = L >> 7, bk_ = L & 127;
        int bsk = bk_ ^ ((rk & 7) << 4);
        gload16((const char*)(Kb + (size_t)(k0 + rk) * 64) + bsk, (char*)(&Kl[buf][0]) + bb);
        int rv = L >> 6, bv = L & 63;
        int bsv = bv ^ (((rv >> 1) & 3) << 4);
        gload16((const char*)(Vb + (size_t)rv * 2048 + k0) + bsv, (char*)(&Vl[buf][0]) + bb);
    };

    stage(0, 0);
    stage(1, 32);
    stage(2, 64);
    wait4_barrier();

    for (int t = 0; t < 64; ++t) {
        const int cur = t & 3;
        if (t + 3 < 64) stage((t + 3) & 3, (t + 3) * 32);
        const char* Kc = (const char*)&Kl[cur][0];
        const char* Vc = (const char*)&Vl[cur][0];

        f32x4 s[2][2] = {};
        __builtin_amdgcn_s_setprio(1);
#pragma unroll
        for (int kk = 0; kk < 2; ++kk) {
            bf16x8 kf[2];
#pragma unroll
            for (int n = 0; n < 2; ++n) {
                int key = n * 16 + l15;
                kf[n] = *(const bf16x8*)(Kc + key * 128 +
                         ((kk * 64 + g * 16) ^ ((key & 7) << 4)));
            }
#pragma unroll
            for (int m = 0; m < 2; ++m)
#pragma unroll
                for (int n = 0; n < 2; ++n)
                    s[m][n] = __builtin_amdgcn_mfma_f32_16x16x32_bf16(kf[n], qf[m][kk], s[m][n], 0, 0, 0);
        }
        __builtin_amdgcn_s_setprio(0);

        short* P = &Pl[w][0];
#pragma unroll
        for (int m = 0; m < 2; ++m) {
            int qr = m * 16 + l15;
            char* prow = (char*)P + qr * 64;
            int sw = ((qr >> 1) & 3) << 4;
#pragma unroll
            for (int n = 0; n < 2; ++n) {
                float e0 = __builtin_amdgcn_exp2f(s[m][n][0]);
                float e1 = __builtin_amdgcn_exp2f(s[m][n][1]);
                float e2 = __builtin_amdgcn_exp2f(s[m][n][2]);
                float e3 = __builtin_amdgcn_exp2f(s[m][n][3]);
                lpart[m] += (e0 + e1) + (e2 + e3);
                int keyb = n * 32 + g * 8;
                uint2 pk; pk.x = cvtpk(e0, e1); pk.y = cvtpk(e2, e3);
                *(uint2*)(prow + (keyb ^ sw)) = pk;
            }
        }

        __builtin_amdgcn_s_setprio(1);
        {
            bf16x8 vf[4], pf[2];
#pragma unroll
            for (int n = 0; n < 4; ++n) {
                int d = n * 16 + l15;
                vf[n] = *(const bf16x8*)(Vc + d * 64 + ((g * 16) ^ (((d >> 1) & 3) << 4)));
            }
#pragma unroll
            for (int m = 0; m < 2; ++m) {
                int qr = m * 16 + l15;
                pf[m] = *(const bf16x8*)((const char*)P + qr * 64 + ((g * 16) ^ (((qr >> 1) & 3) << 4)));
            }
#pragma unroll
            for (int m = 0; m < 2; ++m)
#pragma unroll
                for (int n = 0; n < 4; ++n)
                    accO[m][n] = __builtin_amdgcn_mfma_f32_16x16x32_bf16(pf[m], vf[n], accO[m][n], 0, 0, 0);
        }
        __builtin_amdgcn_s_setprio(0);

        if (t < 61)       wait4_barrier();
        else if (t == 61) wait2_barrier();
        else if (t == 62) wait0_barrier();
    }

#pragma unroll
    for (int m = 0; m < 2; ++m) {
        lpart[m] += __shfl_xor(lpart[m], 16, 64);
        lpart[m] += __shfl_xor(lpart[m], 32, 64);
    }

    int b_ = bh / 12, h = bh % 12;
#pragma unroll
    for (int m = 0; m < 2; ++m) {
        float linv[4];
#pragma unroll
        for (int j = 0; j < 4; ++j)
            linv[j] = 1.0f / __shfl(lpart[m], g * 4 + j, 64);
#pragma unroll
        for (int n = 0; n < 4; ++n)
#pragma unroll
            for (int j = 0; j < 4; ++j) {
                int qq = q0 + m * 16 + g * 4 + j;
                int d = n * 16 + l15;
                Y[((size_t)b_ * 2048 + qq) * 768 + h * 64 + d] = f2bf(accO[m][n][j] * linv[j]);
            }
    }
}

// ---------------- launcher ---------------------------------------------
extern "C" void kernel_launch(void* const* d_in, const int* in_sizes, int n_in,
                              void* d_out, int out_size, void* d_ws, size_t ws_size,
                              hipStream_t stream)
{
    const float* x      = (const float*)d_in[0];
    const float* ln1_g  = (const float*)d_in[1];
    const float* ln1_b  = (const float*)d_in[2];
    const float* w_qkv  = (const float*)d_in[3];
    const float* w_proj = (const float*)d_in[4];
    const float* b_proj = (const float*)d_in[5];
    const float* ln2_g  = (const float*)d_in[6];
    const float* ln2_b  = (const float*)d_in[7];
    const float* w_fc1  = (const float*)d_in[8];
    const float* b_fc1  = (const float*)d_in[9];
    const float* w_fc2  = (const float*)d_in[10];
    const float* b_fc2  = (const float*)d_in[11];

    char* ws = (char*)d_ws;
    size_t off = 0;
    auto alloc = [&](size_t bytes) -> void* {
        void* p = ws + off; off += (bytes + 255) & ~(size_t)255; return p;
    };
    short* wqkvT = (short*)alloc((size_t)2304 * 768 * 2);
    short* wprojT= (short*)alloc((size_t)768 * 768 * 2);
    short* wfc1T = (short*)alloc((size_t)3072 * 768 * 2);
    short* wfc2T = (short*)alloc((size_t)768 * 3072 * 2);
    short* h1    = (short*)alloc((size_t)8192 * 768 * 2);
    short* qb    = (short*)alloc((size_t)48 * 2048 * 64 * 2);
    short* kb    = (short*)alloc((size_t)48 * 2048 * 64 * 2);
    short* vtb   = (short*)alloc((size_t)48 * 64 * 2048 * 2);
    short* yb    = (short*)alloc((size_t)8192 * 768 * 2);
    float* X1    = (float*)alloc((size_t)8192 * 768 * 4);
    short* h2    = (short*)alloc((size_t)8192 * 768 * 2);
    short* h3    = (short*)alloc((size_t)8192 * 3072 * 2);

    hipFuncSetAttribute((const void*)gemm256<0>, hipFuncAttributeMaxDynamicSharedMemorySize, 131072);
    hipFuncSetAttribute((const void*)gemm256<2>, hipFuncAttributeMaxDynamicSharedMemorySize, 131072);

    tcvt<<<dim3(2304 / 32, 768 / 32),  256, 0, stream>>>(w_qkv,  wqkvT,  768,  2304);
    tcvt<<<dim3(768 / 32,  768 / 32),  256, 0, stream>>>(w_proj, wprojT, 768,  768);
    tcvt<<<dim3(3072 / 32, 768 / 32),  256, 0, stream>>>(w_fc1,  wfc1T,  768,  3072);
    tcvt<<<dim3(768 / 32,  3072 / 32), 256, 0, stream>>>(w_fc2,  wfc2T,  3072, 768);

    ln_bf16<<<2048, 256, 0, stream>>>(x, ln1_g, ln1_b, h1);

    gemm256<0><<<dim3(32, 9), 512, 131072, stream>>>(h1, wqkvT, 8192, 2304, 768,
        nullptr, nullptr, qb, kb, vtb);

    attn_fwd<<<dim3(16, 48), 256, 0, stream>>>(qb, kb, vtb, yb);

    gemm_bf16<1><<<dim3(64, 6), 256, 0, stream>>>(yb, wprojT, 8192, 768, 768,
        b_proj, x, X1);

    ln_bf16<<<2048, 256, 0, stream>>>(X1, ln2_g, ln2_b, h2);

    gemm256<2><<<dim3(32, 12), 512, 131072, stream>>>(h2, wfc1T, 8192, 3072, 768,
        b_fc1, h3, nullptr, nullptr, nullptr);

    gemm_bf16<1><<<dim3(64, 6), 256, 0, stream>>>(h3, wfc2T, 8192, 768, 3072,
        b_fc2, X1, (float*)d_out);
}

// Round 7
// 373.796 us; speedup vs baseline: 1.0724x; 1.0724x over previous
//
#include <hip/hip_runtime.h>
#include <stdint.h>

#define DEV __device__ __forceinline__

typedef __attribute__((ext_vector_type(8))) short bf16x8;
typedef __attribute__((ext_vector_type(4))) float f32x4;
typedef __attribute__((ext_vector_type(4))) short s16x4;

DEV short f2bf(float f) {
    union { float f; unsigned u; } v; v.f = f;
    unsigned r = v.u + 0x7fffu + ((v.u >> 16) & 1u);
    return (short)(r >> 16);
}

// packed f32x2 -> bf16x2 (RNE), single VALU op
DEV uint32_t cvtpk(float lo, float hi) {
    uint32_t r;
    asm("v_cvt_pk_bf16_f32 %0, %1, %2" : "=v"(r) : "v"(lo), "v"(hi));
    return r;
}

typedef const unsigned int __attribute__((address_space(1)))* gp1;
typedef unsigned int __attribute__((address_space(3)))* lp3;

DEV void gload16(const void* g, void* l) {
    __builtin_amdgcn_global_load_lds((gp1)g, (lp3)l, 16, 0, 0);
}

DEV void bar()           { asm volatile("s_barrier" ::: "memory"); }
DEV void wait4_barrier() { asm volatile("s_waitcnt vmcnt(4)\ns_barrier" ::: "memory"); }
DEV void wait2_barrier() { asm volatile("s_waitcnt vmcnt(2)\ns_barrier" ::: "memory"); }
DEV void wait0_barrier() { asm volatile("s_waitcnt vmcnt(0)\ns_barrier" ::: "memory"); }

// ---------------- weight transpose + fp32->bf16 convert ----------------
__global__ __launch_bounds__(256) void tcvt(
    const float* __restrict__ W, short* __restrict__ WT, int K, int N)
{
    __shared__ float t[32][33];
    int n0 = blockIdx.x * 32, k0 = blockIdx.y * 32;
    int tx = threadIdx.x & 31, ty = threadIdx.x >> 5;
#pragma unroll
    for (int i = 0; i < 32; i += 8)
        t[ty + i][tx] = W[(size_t)(k0 + ty + i) * N + n0 + tx];
    __syncthreads();
#pragma unroll
    for (int i = 0; i < 32; i += 8)
        WT[(size_t)(n0 + ty + i) * K + k0 + tx] = f2bf(t[tx][ty + i]);
}

// ---------------- LayerNorm fp32 -> bf16, one wave per row (C=768) -----
__global__ __launch_bounds__(256) void ln_bf16(
    const float* __restrict__ x, const float* __restrict__ gam,
    const float* __restrict__ bet, short* __restrict__ out)
{
    const int w = threadIdx.x >> 6, lane = threadIdx.x & 63;
    const size_t row = (size_t)blockIdx.x * 4 + w;
    const float* xr = x + row * 768;
    float4 v[3];
    float s = 0.f, ss = 0.f;
#pragma unroll
    for (int k = 0; k < 3; ++k) {
        v[k] = *(const float4*)(xr + k * 256 + lane * 4);
        s  += v[k].x + v[k].y + v[k].z + v[k].w;
        ss += v[k].x * v[k].x + v[k].y * v[k].y + v[k].z * v[k].z + v[k].w * v[k].w;
    }
#pragma unroll
    for (int i = 1; i < 64; i <<= 1) { s += __shfl_xor(s, i, 64); ss += __shfl_xor(ss, i, 64); }
    const float inv = 1.f / 768.f;
    float mu = s * inv;
    float var = ss * inv - mu * mu;
    float rstd = rsqrtf(var + 1e-5f);
#pragma unroll
    for (int k = 0; k < 3; ++k) {
        int c = k * 256 + lane * 4;
        float vv[4] = { v[k].x, v[k].y, v[k].z, v[k].w };
        s16x4 o;
#pragma unroll
        for (int j = 0; j < 4; ++j)
            o[j] = f2bf((vv[j] - mu) * rstd * gam[c + j] + bet[c + j]);
        *(s16x4*)(out + row * 768 + c) = o;
    }
}

// ---------------- 128x128x32 bf16 GEMM body (r4-proven) ------------------
// Triple-buffered LDS, distance-2 prefetch, counted vmcnt(4) barriers.
// MODE 0: QKV scatter; MODE 1: fp32 = acc+bias+resid; MODE 2: bf16 gelu.
template<int MODE>
DEV void gemm_body(
    const short* __restrict__ A, const short* __restrict__ Bt,
    int M, int N, int K,
    const float* __restrict__ bias, const float* __restrict__ resid,
    float* __restrict__ outf, short* __restrict__ outb,
    short* __restrict__ qo, short* __restrict__ ko, short* __restrict__ vo,
    short (*As)[128 * 32], short (*Bs)[128 * 32])
{
    const int tid = threadIdx.x;
    const int w = tid >> 6, lane = tid & 63;
    const int g = lane >> 4, l15 = lane & 15;
    const int brow = blockIdx.x * 128, bcol = blockIdx.y * 128;
    const int wr = w >> 1, wc = w & 1;
    f32x4 acc[4][4] = {};

    auto stage = [&](int buf, int kt) {
#pragma unroll
        for (int c = 0; c < 2; ++c) {
            int base = w * 2048 + c * 1024;
            int L = base + lane * 16;
            int r = L >> 6;
            int b = L & 63;
            int bs = b ^ (((r >> 1) & 3) << 4);
            gload16((const char*)(A  + (size_t)(brow + r) * K + kt) + bs, (char*)&As[buf][0] + base);
            gload16((const char*)(Bt + (size_t)(bcol + r) * K + kt) + bs, (char*)&Bs[buf][0] + base);
        }
    };

    const int KT = K >> 5;
    stage(0, 0);
    stage(1, 32);
    wait4_barrier();

    int cur = 0;
    for (int ki = 0; ki < KT; ++ki) {
        if (ki + 2 < KT) {
            int nxt2 = cur + 2; if (nxt2 >= 3) nxt2 -= 3;
            stage(nxt2, (ki + 2) << 5);
        }
        bf16x8 af[4], bfg[4];
#pragma unroll
        for (int m = 0; m < 4; ++m) {
            int r = wr * 64 + m * 16 + l15;
            af[m] = *(const bf16x8*)((const char*)&As[cur][0] + r * 64 + ((g * 16) ^ (((r >> 1) & 3) << 4)));
        }
#pragma unroll
        for (int n = 0; n < 4; ++n) {
            int r = wc * 64 + n * 16 + l15;
            bfg[n] = *(const bf16x8*)((const char*)&Bs[cur][0] + r * 64 + ((g * 16) ^ (((r >> 1) & 3) << 4)));
        }
#pragma unroll
        for (int m = 0; m < 4; ++m)
#pragma unroll
            for (int n = 0; n < 4; ++n)
                acc[m][n] = __builtin_amdgcn_mfma_f32_16x16x32_bf16(af[m], bfg[n], acc[m][n], 0, 0, 0);
        if (ki + 1 < KT) {
            if (ki + 2 < KT) wait4_barrier();
            else             wait0_barrier();
        }
        ++cur; if (cur >= 3) cur -= 3;
    }

#pragma unroll
    for (int m = 0; m < 4; ++m) {
#pragma unroll
        for (int n = 0; n < 4; ++n) {
#pragma unroll
            for (int j = 0; j < 4; ++j) {
                int r = brow + wr * 64 + m * 16 + g * 4 + j;
                int c = bcol + wc * 64 + n * 16 + l15;
                float v = acc[m][n][j];
                if (MODE == 0) {
                    int which = c / 768, cc = c % 768;
                    int h = cc >> 6, d = cc & 63;
                    int b_ = r >> 11, nn = r & 2047;
                    size_t bh = (size_t)b_ * 12 + h;
                    if (which == 0)      qo[(bh * 2048 + nn) * 64 + d] = f2bf(v * 0.18033688011112042f);
                    else if (which == 1) ko[(bh * 2048 + nn) * 64 + d] = f2bf(v);
                    else                 vo[(bh * 64 + d) * 2048 + nn] = f2bf(v);
                } else if (MODE == 1) {
                    outf[(size_t)r * N + c] = v + bias[c] + resid[(size_t)r * N + c];
                } else {
                    float t = v + bias[c];
                    float ge = 0.5f * t * (1.0f + erff(t * 0.70710678118654752f));
                    outb[(size_t)r * N + c] = f2bf(ge);
                }
            }
        }
    }
}

// distinct names for rocprof attribution
__global__ __launch_bounds__(256, 3) void g_qkv(
    const short* A, const short* Bt, int M, int N, int K,
    short* qo, short* ko, short* vo)
{
    __shared__ __align__(16) short As[3][128 * 32];
    __shared__ __align__(16) short Bs[3][128 * 32];
    gemm_body<0>(A, Bt, M, N, K, nullptr, nullptr, nullptr, nullptr, qo, ko, vo, As, Bs);
}
__global__ __launch_bounds__(256, 3) void g_proj(
    const short* A, const short* Bt, int M, int N, int K,
    const float* bias, const float* resid, float* outf)
{
    __shared__ __align__(16) short As[3][128 * 32];
    __shared__ __align__(16) short Bs[3][128 * 32];
    gemm_body<1>(A, Bt, M, N, K, bias, resid, outf, nullptr, nullptr, nullptr, nullptr, As, Bs);
}
__global__ __launch_bounds__(256, 3) void g_fc1(
    const short* A, const short* Bt, int M, int N, int K,
    const float* bias, short* outb)
{
    __shared__ __align__(16) short As[3][128 * 32];
    __shared__ __align__(16) short Bs[3][128 * 32];
    gemm_body<2>(A, Bt, M, N, K, bias, nullptr, nullptr, outb, nullptr, nullptr, nullptr, As, Bs);
}
__global__ __launch_bounds__(256, 3) void g_fc2(
    const short* A, const short* Bt, int M, int N, int K,
    const float* bias, const float* resid, float* outf)
{
    __shared__ __align__(16) short As[3][128 * 32];
    __shared__ __align__(16) short Bs[3][128 * 32];
    gemm_body<1>(A, Bt, M, N, K, bias, resid, outf, nullptr, nullptr, nullptr, nullptr, As, Bs);
}

// ============ ABLATION KERNELS (FC1 shape, no stores, asm-sinked) =======
// abl_skel: staging + counted-vmcnt barriers ONLY (no ds_read, no MFMA).
__global__ __launch_bounds__(256, 3) void abl_skel(
    const short* __restrict__ A, const short* __restrict__ Bt, int M, int N, int K)
{
    __shared__ __align__(16) short As[3][128 * 32];
    __shared__ __align__(16) short Bs[3][128 * 32];
    const int tid = threadIdx.x;
    const int w = tid >> 6, lane = tid & 63;
    const int brow = blockIdx.x * 128, bcol = blockIdx.y * 128;

    auto stage = [&](int buf, int kt) {
#pragma unroll
        for (int c = 0; c < 2; ++c) {
            int base = w * 2048 + c * 1024;
            int L = base + lane * 16;
            int r = L >> 6;
            int b = L & 63;
            int bs = b ^ (((r >> 1) & 3) << 4);
            gload16((const char*)(A  + (size_t)(brow + r) * K + kt) + bs, (char*)&As[buf][0] + base);
            gload16((const char*)(Bt + (size_t)(bcol + r) * K + kt) + bs, (char*)&Bs[buf][0] + base);
        }
    };

    const int KT = K >> 5;
    stage(0, 0);
    stage(1, 32);
    wait4_barrier();
    int cur = 0;
    for (int ki = 0; ki < KT; ++ki) {
        if (ki + 2 < KT) {
            int nxt2 = cur + 2; if (nxt2 >= 3) nxt2 -= 3;
            stage(nxt2, (ki + 2) << 5);
        }
        if (ki + 1 < KT) {
            if (ki + 2 < KT) wait4_barrier();
            else             wait0_barrier();
        }
        ++cur; if (cur >= 3) cur -= 3;
    }
    // keep LDS observably live
    int v = *((volatile short*)&As[0][0] + tid);
    asm volatile("" :: "v"(v));
}

// abl_comp: ds_read + MFMA + barriers ONLY (staging stops after prologue).
// bar()'s memory clobber forces the LDS re-reads each iteration.
__global__ __launch_bounds__(256, 3) void abl_comp(
    const short* __restrict__ A, const short* __restrict__ Bt, int M, int N, int K)
{
    __shared__ __align__(16) short As[3][128 * 32];
    __shared__ __align__(16) short Bs[3][128 * 32];
    const int tid = threadIdx.x;
    const int w = tid >> 6, lane = tid & 63;
    const int g = lane >> 4, l15 = lane & 15;
    const int brow = blockIdx.x * 128, bcol = blockIdx.y * 128;
    const int wr = w >> 1, wc = w & 1;
    f32x4 acc[4][4] = {};

    auto stage = [&](int buf, int kt) {
#pragma unroll
        for (int c = 0; c < 2; ++c) {
            int base = w * 2048 + c * 1024;
            int L = base + lane * 16;
            int r = L >> 6;
            int b = L & 63;
            int bs = b ^ (((r >> 1) & 3) << 4);
            gload16((const char*)(A  + (size_t)(brow + r) * K + kt) + bs, (char*)&As[buf][0] + base);
            gload16((const char*)(Bt + (size_t)(bcol + r) * K + kt) + bs, (char*)&Bs[buf][0] + base);
        }
    };

    const int KT = K >> 5;
    stage(0, 0); stage(1, 32); stage(2, 64);   // fill all 3 bufs with real data
    wait0_barrier();

    int cur = 0;
    for (int ki = 0; ki < KT; ++ki) {
        bf16x8 af[4], bfg[4];
#pragma unroll
        for (int m = 0; m < 4; ++m) {
            int r = wr * 64 + m * 16 + l15;
            af[m] = *(const bf16x8*)((const char*)&As[cur][0] + r * 64 + ((g * 16) ^ (((r >> 1) & 3) << 4)));
        }
#pragma unroll
        for (int n = 0; n < 4; ++n) {
            int r = wc * 64 + n * 16 + l15;
            bfg[n] = *(const bf16x8*)((const char*)&Bs[cur][0] + r * 64 + ((g * 16) ^ (((r >> 1) & 3) << 4)));
        }
#pragma unroll
        for (int m = 0; m < 4; ++m)
#pragma unroll
            for (int n = 0; n < 4; ++n)
                acc[m][n] = __builtin_amdgcn_mfma_f32_16x16x32_bf16(af[m], bfg[n], acc[m][n], 0, 0, 0);
        if (ki + 1 < KT) bar();                 // memory clobber: no hoisting
        ++cur; if (cur >= 3) cur -= 3;
    }
#pragma unroll
    for (int m = 0; m < 4; ++m)
#pragma unroll
        for (int n = 0; n < 4; ++n)
#pragma unroll
            for (int j = 0; j < 4; ++j)
                asm volatile("" :: "v"(acc[m][n][j]));
}

// ---------------- flash attention (r4-proven) ---------------------------
__global__ __launch_bounds__(256, 4) void attn_fwd(
    const short* __restrict__ Q, const short* __restrict__ Kg,
    const short* __restrict__ Vt, short* __restrict__ Y)
{
    __shared__ __align__(16) short Kl[4][32 * 64];
    __shared__ __align__(16) short Vl[4][64 * 32];
    __shared__ __align__(16) short Pl[4][32 * 32];
    const int tid = threadIdx.x, w = tid >> 6, lane = tid & 63;
    const int g = lane >> 4, l15 = lane & 15;
    const int bh = blockIdx.y;
    const int q0 = blockIdx.x * 128 + w * 32;
    const short* Qb = Q  + (size_t)bh * 2048 * 64;
    const short* Kb = Kg + (size_t)bh * 2048 * 64;
    const short* Vb = Vt + (size_t)bh * 64 * 2048;

    bf16x8 qf[2][2];
#pragma unroll
    for (int m = 0; m < 2; ++m)
#pragma unroll
        for (int kk = 0; kk < 2; ++kk)
            qf[m][kk] = *(const bf16x8*)(Qb + (size_t)(q0 + m * 16 + l15) * 64 + kk * 32 + g * 8);

    f32x4 accO[2][4] = {};
    float lpart[2] = { 0.f, 0.f };

    auto stage = [&](int buf, int k0) {
        int bb = w * 1024;
        int L = bb + lane * 16;
        int rk = L >> 7, bk_ = L & 127;
        int bsk = bk_ ^ ((rk & 7) << 4);
        gload16((const char*)(Kb + (size_t)(k0 + rk) * 64) + bsk, (char*)(&Kl[buf][0]) + bb);
        int rv = L >> 6, bv = L & 63;
        int bsv = bv ^ (((rv >> 1) & 3) << 4);
        gload16((const char*)(Vb + (size_t)rv * 2048 + k0) + bsv, (char*)(&Vl[buf][0]) + bb);
    };

    stage(0, 0);
    stage(1, 32);
    stage(2, 64);
    wait4_barrier();

    for (int t = 0; t < 64; ++t) {
        const int cur = t & 3;
        if (t + 3 < 64) stage((t + 3) & 3, (t + 3) * 32);
        const char* Kc = (const char*)&Kl[cur][0];
        const char* Vc = (const char*)&Vl[cur][0];

        f32x4 s[2][2] = {};
        __builtin_amdgcn_s_setprio(1);
#pragma unroll
        for (int kk = 0; kk < 2; ++kk) {
            bf16x8 kf[2];
#pragma unroll
            for (int n = 0; n < 2; ++n) {
                int key = n * 16 + l15;
                kf[n] = *(const bf16x8*)(Kc + key * 128 +
                         ((kk * 64 + g * 16) ^ ((key & 7) << 4)));
            }
#pragma unroll
            for (int m = 0; m < 2; ++m)
#pragma unroll
                for (int n = 0; n < 2; ++n)
                    s[m][n] = __builtin_amdgcn_mfma_f32_16x16x32_bf16(kf[n], qf[m][kk], s[m][n], 0, 0, 0);
        }
        __builtin_amdgcn_s_setprio(0);

        short* P = &Pl[w][0];
#pragma unroll
        for (int m = 0; m < 2; ++m) {
            int qr = m * 16 + l15;
            char* prow = (char*)P + qr * 64;
            int sw = ((qr >> 1) & 3) << 4;
#pragma unroll
            for (int n = 0; n < 2; ++n) {
                float e0 = __builtin_amdgcn_exp2f(s[m][n][0]);
                float e1 = __builtin_amdgcn_exp2f(s[m][n][1]);
                float e2 = __builtin_amdgcn_exp2f(s[m][n][2]);
                float e3 = __builtin_amdgcn_exp2f(s[m][n][3]);
                lpart[m] += (e0 + e1) + (e2 + e3);
                int keyb = n * 32 + g * 8;
                uint2 pk; pk.x = cvtpk(e0, e1); pk.y = cvtpk(e2, e3);
                *(uint2*)(prow + (keyb ^ sw)) = pk;
            }
        }

        __builtin_amdgcn_s_setprio(1);
        {
            bf16x8 vf[4], pf[2];
#pragma unroll
            for (int n = 0; n < 4; ++n) {
                int d = n * 16 + l15;
                vf[n] = *(const bf16x8*)(Vc + d * 64 + ((g * 16) ^ (((d >> 1) & 3) << 4)));
            }
#pragma unroll
            for (int m = 0; m < 2; ++m) {
                int qr = m * 16 + l15;
                pf[m] = *(const bf16x8*)((const char*)P + qr * 64 + ((g * 16) ^ (((qr >> 1) & 3) << 4)));
            }
#pragma unroll
            for (int m = 0; m < 2; ++m)
#pragma unroll
                for (int n = 0; n < 4; ++n)
                    accO[m][n] = __builtin_amdgcn_mfma_f32_16x16x32_bf16(pf[m], vf[n], accO[m][n], 0, 0, 0);
        }
        __builtin_amdgcn_s_setprio(0);

        if (t < 61)       wait4_barrier();
        else if (t == 61) wait2_barrier();
        else if (t == 62) wait0_barrier();
    }

#pragma unroll
    for (int m = 0; m < 2; ++m) {
        lpart[m] += __shfl_xor(lpart[m], 16, 64);
        lpart[m] += __shfl_xor(lpart[m], 32, 64);
    }

    int b_ = bh / 12, h = bh % 12;
#pragma unroll
    for (int m = 0; m < 2; ++m) {
        float linv[4];
#pragma unroll
        for (int j = 0; j < 4; ++j)
            linv[j] = 1.0f / __shfl(lpart[m], g * 4 + j, 64);
#pragma unroll
        for (int n = 0; n < 4; ++n)
#pragma unroll
            for (int j = 0; j < 4; ++j) {
                int qq = q0 + m * 16 + g * 4 + j;
                int d = n * 16 + l15;
                Y[((size_t)b_ * 2048 + qq) * 768 + h * 64 + d] = f2bf(accO[m][n][j] * linv[j]);
            }
    }
}

// ---------------- launcher ---------------------------------------------
extern "C" void kernel_launch(void* const* d_in, const int* in_sizes, int n_in,
                              void* d_out, int out_size, void* d_ws, size_t ws_size,
                              hipStream_t stream)
{
    const float* x      = (const float*)d_in[0];
    const float* ln1_g  = (const float*)d_in[1];
    const float* ln1_b  = (const float*)d_in[2];
    const float* w_qkv  = (const float*)d_in[3];
    const float* w_proj = (const float*)d_in[4];
    const float* b_proj = (const float*)d_in[5];
    const float* ln2_g  = (const float*)d_in[6];
    const float* ln2_b  = (const float*)d_in[7];
    const float* w_fc1  = (const float*)d_in[8];
    const float* b_fc1  = (const float*)d_in[9];
    const float* w_fc2  = (const float*)d_in[10];
    const float* b_fc2  = (const float*)d_in[11];

    char* ws = (char*)d_ws;
    size_t off = 0;
    auto alloc = [&](size_t bytes) -> void* {
        void* p = ws + off; off += (bytes + 255) & ~(size_t)255; return p;
    };
    short* wqkvT = (short*)alloc((size_t)2304 * 768 * 2);
    short* wprojT= (short*)alloc((size_t)768 * 768 * 2);
    short* wfc1T = (short*)alloc((size_t)3072 * 768 * 2);
    short* wfc2T = (short*)alloc((size_t)768 * 3072 * 2);
    short* h1    = (short*)alloc((size_t)8192 * 768 * 2);
    short* qb    = (short*)alloc((size_t)48 * 2048 * 64 * 2);
    short* kb    = (short*)alloc((size_t)48 * 2048 * 64 * 2);
    short* vtb   = (short*)alloc((size_t)48 * 64 * 2048 * 2);
    short* yb    = (short*)alloc((size_t)8192 * 768 * 2);
    float* X1    = (float*)alloc((size_t)8192 * 768 * 4);
    short* h2    = (short*)alloc((size_t)8192 * 768 * 2);
    short* h3    = (short*)alloc((size_t)8192 * 3072 * 2);

    tcvt<<<dim3(2304 / 32, 768 / 32),  256, 0, stream>>>(w_qkv,  wqkvT,  768,  2304);
    tcvt<<<dim3(768 / 32,  768 / 32),  256, 0, stream>>>(w_proj, wprojT, 768,  768);
    tcvt<<<dim3(3072 / 32, 768 / 32),  256, 0, stream>>>(w_fc1,  wfc1T,  768,  3072);
    tcvt<<<dim3(768 / 32,  3072 / 32), 256, 0, stream>>>(w_fc2,  wfc2T,  3072, 768);

    ln_bf16<<<2048, 256, 0, stream>>>(x, ln1_g, ln1_b, h1);

    g_qkv<<<dim3(64, 18), 256, 0, stream>>>(h1, wqkvT, 8192, 2304, 768, qb, kb, vtb);

    attn_fwd<<<dim3(16, 48), 256, 0, stream>>>(qb, kb, vtb, yb);

    g_proj<<<dim3(64, 6), 256, 0, stream>>>(yb, wprojT, 8192, 768, 768, b_proj, x, X1);

    ln_bf16<<<2048, 256, 0, stream>>>(X1, ln2_g, ln2_b, h2);

    g_fc1<<<dim3(64, 24), 256, 0, stream>>>(h2, wfc1T, 8192, 3072, 768, b_fc1, h3);

    g_fc2<<<dim3(64, 6), 256, 0, stream>>>(h3, wfc2T, 8192, 768, 3072, b_fc2, X1, (float*)d_out);

    // --- ablation dispatches (FC1 shape; no stores; decomposition probes) ---
    abl_skel<<<dim3(64, 24), 256, 0, stream>>>(h2, wfc1T, 8192, 3072, 768);
    abl_comp<<<dim3(64, 24), 256, 0, stream>>>(h2, wfc1T, 8192, 3072, 768);
}

// Round 8
// 274.647 us; speedup vs baseline: 1.4596x; 1.3610x over previous
//
#include <hip/hip_runtime.h>
#include <stdint.h>

#define DEV __device__ __forceinline__

typedef __attribute__((ext_vector_type(8))) short bf16x8;
typedef __attribute__((ext_vector_type(4))) float f32x4;
typedef __attribute__((ext_vector_type(4))) short s16x4;

DEV short f2bf(float f) {
    union { float f; unsigned u; } v; v.f = f;
    unsigned r = v.u + 0x7fffu + ((v.u >> 16) & 1u);
    return (short)(r >> 16);
}

// packed f32x2 -> bf16x2 (RNE), single VALU op
DEV uint32_t cvtpk(float lo, float hi) {
    uint32_t r;
    asm("v_cvt_pk_bf16_f32 %0, %1, %2" : "=v"(r) : "v"(lo), "v"(hi));
    return r;
}

typedef const unsigned int __attribute__((address_space(1)))* gp1;
typedef unsigned int __attribute__((address_space(3)))* lp3;

DEV void gload16(const void* g, void* l) {
    __builtin_amdgcn_global_load_lds((gp1)g, (lp3)l, 16, 0, 0);
}

DEV void wait4_barrier() { asm volatile("s_waitcnt vmcnt(4)\ns_barrier" ::: "memory"); }
DEV void wait2_barrier() { asm volatile("s_waitcnt vmcnt(2)\ns_barrier" ::: "memory"); }
DEV void wait0_barrier() { asm volatile("s_waitcnt vmcnt(0)\ns_barrier" ::: "memory"); }

// ---------------- weight transpose + fp32->bf16 convert ----------------
__global__ __launch_bounds__(256) void tcvt(
    const float* __restrict__ W, short* __restrict__ WT, int K, int N)
{
    __shared__ float t[32][33];
    int n0 = blockIdx.x * 32, k0 = blockIdx.y * 32;
    int tx = threadIdx.x & 31, ty = threadIdx.x >> 5;
#pragma unroll
    for (int i = 0; i < 32; i += 8)
        t[ty + i][tx] = W[(size_t)(k0 + ty + i) * N + n0 + tx];
    __syncthreads();
#pragma unroll
    for (int i = 0; i < 32; i += 8)
        WT[(size_t)(n0 + ty + i) * K + k0 + tx] = f2bf(t[tx][ty + i]);
}

// ---------------- LayerNorm fp32 -> bf16, one wave per row (C=768) -----
__global__ __launch_bounds__(256) void ln_bf16(
    const float* __restrict__ x, const float* __restrict__ gam,
    const float* __restrict__ bet, short* __restrict__ out)
{
    const int w = threadIdx.x >> 6, lane = threadIdx.x & 63;
    const size_t row = (size_t)blockIdx.x * 4 + w;
    const float* xr = x + row * 768;
    float4 v[3];
    float s = 0.f, ss = 0.f;
#pragma unroll
    for (int k = 0; k < 3; ++k) {
        v[k] = *(const float4*)(xr + k * 256 + lane * 4);
        s  += v[k].x + v[k].y + v[k].z + v[k].w;
        ss += v[k].x * v[k].x + v[k].y * v[k].y + v[k].z * v[k].z + v[k].w * v[k].w;
    }
#pragma unroll
    for (int i = 1; i < 64; i <<= 1) { s += __shfl_xor(s, i, 64); ss += __shfl_xor(ss, i, 64); }
    const float inv = 1.f / 768.f;
    float mu = s * inv;
    float var = ss * inv - mu * mu;
    float rstd = rsqrtf(var + 1e-5f);
#pragma unroll
    for (int k = 0; k < 3; ++k) {
        int c = k * 256 + lane * 4;
        float vv[4] = { v[k].x, v[k].y, v[k].z, v[k].w };
        s16x4 o;
#pragma unroll
        for (int j = 0; j < 4; ++j)
            o[j] = f2bf((vv[j] - mu) * rstd * gam[c + j] + bet[c + j]);
        *(s16x4*)(out + row * 768 + c) = o;
    }
}

// ---------------- 128x128x32 bf16 GEMM body -----------------------------
// r4 sync structure (3-buffer, distance-2 prefetch, counted vmcnt(4)),
// K-loop unrolled x3 so the buffer index is compile-time: all ds_read /
// staging addresses are loop-invariant VGPRs + constant imm offsets.
// LDS layout (one 48KB block): buf b at [b*16384): A tile 8KB then B tile 8KB.
template<int MODE>
DEV void gemm_body(
    const short* __restrict__ A, const short* __restrict__ Bt,
    int M, int N, int K,
    const float* __restrict__ bias, const float* __restrict__ resid,
    float* __restrict__ outf, short* __restrict__ outb,
    short* __restrict__ qo, short* __restrict__ ko, short* __restrict__ vo,
    char* lds)
{
    const int tid = threadIdx.x;
    const int w = tid >> 6, lane = tid & 63;
    const int g = lane >> 4, l15 = lane & 15;
    const int brow = blockIdx.x * 128, bcol = blockIdx.y * 128;
    const int wr = w >> 1, wc = w & 1;
    f32x4 acc[4][4] = {};

    // loop-invariant LDS read byte-offsets (within one 16KB buffer)
    int aoff[4], boff[4];
#pragma unroll
    for (int m = 0; m < 4; ++m) {
        int ra = wr * 64 + m * 16 + l15;
        aoff[m] = ra * 64 + ((g * 16) ^ (((ra >> 1) & 3) << 4));
        int rb = wc * 64 + m * 16 + l15;
        boff[m] = 8192 + rb * 64 + ((g * 16) ^ (((rb >> 1) & 3) << 4));
    }
    // loop-invariant staging addresses (dest wave-uniform; src per-lane)
    int dA[2], dB[2];
    const char* pA[2]; const char* pB[2];
#pragma unroll
    for (int c = 0; c < 2; ++c) {
        int base = w * 2048 + c * 1024;
        int L = base + lane * 16;
        int r = L >> 6, b = L & 63;
        int bs = b ^ (((r >> 1) & 3) << 4);
        dA[c] = base; dB[c] = 8192 + base;
        pA[c] = (const char*)(A  + (size_t)(brow + r) * K) + bs;
        pB[c] = (const char*)(Bt + (size_t)(bcol + r) * K) + bs;
    }

#define GSTAGE(BUF, OFF) do { \
    gload16(pA[0] + (OFF), lds + (BUF) * 16384 + dA[0]); \
    gload16(pA[1] + (OFF), lds + (BUF) * 16384 + dA[1]); \
    gload16(pB[0] + (OFF), lds + (BUF) * 16384 + dB[0]); \
    gload16(pB[1] + (OFF), lds + (BUF) * 16384 + dB[1]); } while (0)

    const int KT = K >> 5;            // 24 or 96: divisible by 3
    GSTAGE(0, 0);
    GSTAGE(1, 64);
    wait4_barrier();                  // buf0's 4 loads done; buf1's in flight

    const int NM = KT / 3;
    for (int mi = 0; mi < NM; ++mi) {
#pragma unroll
        for (int u = 0; u < 3; ++u) {
            const int s = mi * 3 + u;
            if (s + 2 < KT) GSTAGE((u + 2) % 3, (u + 2) * 64);
            bf16x8 af[4], bfg[4];
#pragma unroll
            for (int m = 0; m < 4; ++m) {
                af[m]  = *(const bf16x8*)(lds + u * 16384 + aoff[m]);
                bfg[m] = *(const bf16x8*)(lds + u * 16384 + boff[m]);
            }
#pragma unroll
            for (int m = 0; m < 4; ++m)
#pragma unroll
                for (int n = 0; n < 4; ++n)
                    acc[m][n] = __builtin_amdgcn_mfma_f32_16x16x32_bf16(af[m], bfg[n], acc[m][n], 0, 0, 0);
            if (s + 1 < KT) {
                if (s + 2 < KT) wait4_barrier();
                else            wait0_barrier();
            }
        }
        pA[0] += 192; pA[1] += 192; pB[0] += 192; pB[1] += 192;
    }
#undef GSTAGE

#pragma unroll
    for (int m = 0; m < 4; ++m) {
#pragma unroll
        for (int n = 0; n < 4; ++n) {
#pragma unroll
            for (int j = 0; j < 4; ++j) {
                int r = brow + wr * 64 + m * 16 + g * 4 + j;
                int c = bcol + wc * 64 + n * 16 + l15;
                float v = acc[m][n][j];
                if (MODE == 0) {
                    int which = c / 768, cc = c % 768;
                    int h = cc >> 6, d = cc & 63;
                    int b_ = r >> 11, nn = r & 2047;
                    size_t bh = (size_t)b_ * 12 + h;
                    if (which == 0)      qo[(bh * 2048 + nn) * 64 + d] = f2bf(v * 0.18033688011112042f);
                    else if (which == 1) ko[(bh * 2048 + nn) * 64 + d] = f2bf(v);
                    else                 vo[(bh * 64 + d) * 2048 + nn] = f2bf(v);
                } else if (MODE == 1) {
                    outf[(size_t)r * N + c] = v + bias[c] + resid[(size_t)r * N + c];
                } else {
                    float t = v + bias[c];
                    float ge = 0.5f * t * (1.0f + erff(t * 0.70710678118654752f));
                    outb[(size_t)r * N + c] = f2bf(ge);
                }
            }
        }
    }
}

__global__ __launch_bounds__(256, 3) void g_qkv(
    const short* A, const short* Bt, int M, int N, int K,
    short* qo, short* ko, short* vo)
{
    __shared__ __align__(16) char lds[49152];
    gemm_body<0>(A, Bt, M, N, K, nullptr, nullptr, nullptr, nullptr, qo, ko, vo, lds);
}
__global__ __launch_bounds__(256, 3) void g_proj(
    const short* A, const short* Bt, int M, int N, int K,
    const float* bias, const float* resid, float* outf)
{
    __shared__ __align__(16) char lds[49152];
    gemm_body<1>(A, Bt, M, N, K, bias, resid, outf, nullptr, nullptr, nullptr, nullptr, lds);
}
__global__ __launch_bounds__(256, 3) void g_fc1(
    const short* A, const short* Bt, int M, int N, int K,
    const float* bias, short* outb)
{
    __shared__ __align__(16) char lds[49152];
    gemm_body<2>(A, Bt, M, N, K, bias, nullptr, nullptr, outb, nullptr, nullptr, nullptr, lds);
}
__global__ __launch_bounds__(256, 3) void g_fc2(
    const short* A, const short* Bt, int M, int N, int K,
    const float* bias, const float* resid, float* outf)
{
    __shared__ __align__(16) char lds[49152];
    gemm_body<1>(A, Bt, M, N, K, bias, resid, outf, nullptr, nullptr, nullptr, nullptr, lds);
}

// ---------------- flash attention -------------------------------------
// r4 structure (KVBLK=32, quad-buffer, distance-3 prefetch, vmcnt(4));
// t-loop unrolled x4 so the buffer index is compile-time; all LDS offsets
// precomputed per-lane. LDS layout (40960B): K bufs at [buf*4096),
// V bufs at [16384 + buf*4096), P per-wave at [32768 + w*2048).
__global__ __launch_bounds__(256, 3) void attn_fwd(
    const short* __restrict__ Q, const short* __restrict__ Kg,
    const short* __restrict__ Vt, short* __restrict__ Y)
{
    __shared__ __align__(16) char alds[40960];
    const int tid = threadIdx.x, w = tid >> 6, lane = tid & 63;
    const int g = lane >> 4, l15 = lane & 15;
    const int bh = blockIdx.y;
    const int q0 = blockIdx.x * 128 + w * 32;
    const short* Qb = Q  + (size_t)bh * 2048 * 64;
    const short* Kb = Kg + (size_t)bh * 2048 * 64;
    const short* Vb = Vt + (size_t)bh * 64 * 2048;

    bf16x8 qf[2][2];
#pragma unroll
    for (int m = 0; m < 2; ++m)
#pragma unroll
        for (int kk = 0; kk < 2; ++kk)
            qf[m][kk] = *(const bf16x8*)(Qb + (size_t)(q0 + m * 16 + l15) * 64 + kk * 32 + g * 8);

    f32x4 accO[2][4] = {};
    float lpart[2] = { 0.f, 0.f };

    // loop-invariant LDS read/write offsets
    int koff[2][2], voff[4], poff[2], pwoff[2][2];
#pragma unroll
    for (int n = 0; n < 2; ++n) {
        int key = n * 16 + l15;
#pragma unroll
        for (int kk = 0; kk < 2; ++kk)
            koff[kk][n] = key * 128 + ((kk * 64 + g * 16) ^ ((key & 7) << 4));
    }
#pragma unroll
    for (int n = 0; n < 4; ++n) {
        int d = n * 16 + l15;
        voff[n] = 16384 + d * 64 + ((g * 16) ^ (((d >> 1) & 3) << 4));
    }
#pragma unroll
    for (int m = 0; m < 2; ++m) {
        int qr = m * 16 + l15;
        int sw = ((qr >> 1) & 3) << 4;
        poff[m] = 32768 + w * 2048 + qr * 64 + ((g * 16) ^ sw);
#pragma unroll
        for (int n = 0; n < 2; ++n)
            pwoff[m][n] = 32768 + w * 2048 + qr * 64 + ((n * 32 + g * 8) ^ sw);
    }
    // staging invariants
    int dK, dV; const char* pK3; const char* pV3;
    {
        int bb = w * 1024;
        int L = bb + lane * 16;
        int rk = L >> 7, bk_ = L & 127;
        int bsk = bk_ ^ ((rk & 7) << 4);
        dK = bb;
        pK3 = (const char*)(Kb + (size_t)rk * 64) + bsk;
        int rv = L >> 6, bv = L & 63;
        int bsv = bv ^ (((rv >> 1) & 3) << 4);
        dV = bb;
        pV3 = (const char*)(Vb + (size_t)rv * 2048) + bsv;
    }
    // prologue: stage tiles 0,1,2 (K then V per tile, as before)
    gload16(pK3,        alds + dK);
    gload16(pV3,        alds + 16384 + dV);
    gload16(pK3 + 4096, alds + dK + 4096);
    gload16(pV3 + 64,   alds + 16384 + dV + 4096);
    gload16(pK3 + 8192, alds + dK + 8192);
    gload16(pV3 + 128,  alds + 16384 + dV + 8192);
    pK3 += 3 * 4096; pV3 += 3 * 64;   // now point at tile 3
    wait4_barrier();                  // tile0's K,V done; 4 in flight

    for (int tm = 0; tm < 16; ++tm) {
#pragma unroll
        for (int tu = 0; tu < 4; ++tu) {
            const int t = tm * 4 + tu;
            if (t + 3 < 64) {
                gload16(pK3, alds + dK + ((tu + 3) & 3) * 4096);
                gload16(pV3, alds + 16384 + dV + ((tu + 3) & 3) * 4096);
                pK3 += 4096; pV3 += 64;
            }

            f32x4 s2[2][2] = {};
            __builtin_amdgcn_s_setprio(1);
#pragma unroll
            for (int kk = 0; kk < 2; ++kk) {
                bf16x8 kf[2];
#pragma unroll
                for (int n = 0; n < 2; ++n)
                    kf[n] = *(const bf16x8*)(alds + tu * 4096 + koff[kk][n]);
#pragma unroll
                for (int m = 0; m < 2; ++m)
#pragma unroll
                    for (int n = 0; n < 2; ++n)
                        s2[m][n] = __builtin_amdgcn_mfma_f32_16x16x32_bf16(kf[n], qf[m][kk], s2[m][n], 0, 0, 0);
            }
            __builtin_amdgcn_s_setprio(0);

#pragma unroll
            for (int m = 0; m < 2; ++m)
#pragma unroll
                for (int n = 0; n < 2; ++n) {
                    float e0 = __builtin_amdgcn_exp2f(s2[m][n][0]);
                    float e1 = __builtin_amdgcn_exp2f(s2[m][n][1]);
                    float e2 = __builtin_amdgcn_exp2f(s2[m][n][2]);
                    float e3 = __builtin_amdgcn_exp2f(s2[m][n][3]);
                    lpart[m] += (e0 + e1) + (e2 + e3);
                    uint2 pk; pk.x = cvtpk(e0, e1); pk.y = cvtpk(e2, e3);
                    *(uint2*)(alds + pwoff[m][n]) = pk;
                }

            __builtin_amdgcn_s_setprio(1);
            {
                bf16x8 vf[4], pf[2];
#pragma unroll
                for (int n = 0; n < 4; ++n)
                    vf[n] = *(const bf16x8*)(alds + tu * 4096 + voff[n]);
#pragma unroll
                for (int m = 0; m < 2; ++m)
                    pf[m] = *(const bf16x8*)(alds + poff[m]);
#pragma unroll
                for (int m = 0; m < 2; ++m)
#pragma unroll
                    for (int n = 0; n < 4; ++n)
                        accO[m][n] = __builtin_amdgcn_mfma_f32_16x16x32_bf16(pf[m], vf[n], accO[m][n], 0, 0, 0);
            }
            __builtin_amdgcn_s_setprio(0);

            if (t < 61)       wait4_barrier();
            else if (t == 61) wait2_barrier();
            else if (t == 62) wait0_barrier();
        }
    }

#pragma unroll
    for (int m = 0; m < 2; ++m) {
        lpart[m] += __shfl_xor(lpart[m], 16, 64);
        lpart[m] += __shfl_xor(lpart[m], 32, 64);
    }

    int b_ = bh / 12, h = bh % 12;
#pragma unroll
    for (int m = 0; m < 2; ++m) {
        float linv[4];
#pragma unroll
        for (int j = 0; j < 4; ++j)
            linv[j] = 1.0f / __shfl(lpart[m], g * 4 + j, 64);
#pragma unroll
        for (int n = 0; n < 4; ++n)
#pragma unroll
            for (int j = 0; j < 4; ++j) {
                int qq = q0 + m * 16 + g * 4 + j;
                int d = n * 16 + l15;
                Y[((size_t)b_ * 2048 + qq) * 768 + h * 64 + d] = f2bf(accO[m][n][j] * linv[j]);
            }
    }
}

// ---------------- launcher ---------------------------------------------
extern "C" void kernel_launch(void* const* d_in, const int* in_sizes, int n_in,
                              void* d_out, int out_size, void* d_ws, size_t ws_size,
                              hipStream_t stream)
{
    const float* x      = (const float*)d_in[0];
    const float* ln1_g  = (const float*)d_in[1];
    const float* ln1_b  = (const float*)d_in[2];
    const float* w_qkv  = (const float*)d_in[3];
    const float* w_proj = (const float*)d_in[4];
    const float* b_proj = (const float*)d_in[5];
    const float* ln2_g  = (const float*)d_in[6];
    const float* ln2_b  = (const float*)d_in[7];
    const float* w_fc1  = (const float*)d_in[8];
    const float* b_fc1  = (const float*)d_in[9];
    const float* w_fc2  = (const float*)d_in[10];
    const float* b_fc2  = (const float*)d_in[11];

    char* ws = (char*)d_ws;
    size_t off = 0;
    auto alloc = [&](size_t bytes) -> void* {
        void* p = ws + off; off += (bytes + 255) & ~(size_t)255; return p;
    };
    short* wqkvT = (short*)alloc((size_t)2304 * 768 * 2);
    short* wprojT= (short*)alloc((size_t)768 * 768 * 2);
    short* wfc1T = (short*)alloc((size_t)3072 * 768 * 2);
    short* wfc2T = (short*)alloc((size_t)768 * 3072 * 2);
    short* h1    = (short*)alloc((size_t)8192 * 768 * 2);
    short* qb    = (short*)alloc((size_t)48 * 2048 * 64 * 2);
    short* kb    = (short*)alloc((size_t)48 * 2048 * 64 * 2);
    short* vtb   = (short*)alloc((size_t)48 * 64 * 2048 * 2);
    short* yb    = (short*)alloc((size_t)8192 * 768 * 2);
    float* X1    = (float*)alloc((size_t)8192 * 768 * 4);
    short* h2    = (short*)alloc((size_t)8192 * 768 * 2);
    short* h3    = (short*)alloc((size_t)8192 * 3072 * 2);

    tcvt<<<dim3(2304 / 32, 768 / 32),  256, 0, stream>>>(w_qkv,  wqkvT,  768,  2304);
    tcvt<<<dim3(768 / 32,  768 / 32),  256, 0, stream>>>(w_proj, wprojT, 768,  768);
    tcvt<<<dim3(3072 / 32, 768 / 32),  256, 0, stream>>>(w_fc1,  wfc1T,  768,  3072);
    tcvt<<<dim3(768 / 32,  3072 / 32), 256, 0, stream>>>(w_fc2,  wfc2T,  3072, 768);

    ln_bf16<<<2048, 256, 0, stream>>>(x, ln1_g, ln1_b, h1);

    g_qkv<<<dim3(64, 18), 256, 0, stream>>>(h1, wqkvT, 8192, 2304, 768, qb, kb, vtb);

    attn_fwd<<<dim3(16, 48), 256, 0, stream>>>(qb, kb, vtb, yb);

    g_proj<<<dim3(64, 6), 256, 0, stream>>>(yb, wprojT, 8192, 768, 768, b_proj, x, X1);

    ln_bf16<<<2048, 256, 0, stream>>>(X1, ln2_g, ln2_b, h2);

    g_fc1<<<dim3(64, 24), 256, 0, stream>>>(h2, wfc1T, 8192, 3072, 768, b_fc1, h3);

    g_fc2<<<dim3(64, 6), 256, 0, stream>>>(h3, wfc2T, 8192, 768, 3072, b_fc2, X1, (float*)d_out);
}